// Round 1
// baseline (530.877 us; speedup 1.0000x reference)
//
#include <hip/hip_runtime.h>

#define Nn   768
#define Bb   2
#define Uu   64
#define Kk   16
#define DIN  144   // 2U+K
#define TJ   16    // columns per block
#define ICH  8     // i-chunks
#define ILEN (Nn / ICH)  // 96

// ---------- degree ----------
__global__ __launch_bounds__(256) void deg_kernel(const int* __restrict__ mask,
                                                  float* __restrict__ inv_deg) {
  int i = blockIdx.x;
  int t = threadIdx.x;
  int sum = 0;
  for (int j = t; j < Nn; j += 256) sum += mask[i * Nn + j];
  for (int off = 32; off > 0; off >>= 1) sum += __shfl_down(sum, off, 64);
  __shared__ int partial[4];
  if ((t & 63) == 0) partial[t >> 6] = sum;
  __syncthreads();
  if (t == 0) {
    int s = partial[0] + partial[1] + partial[2] + partial[3];
    inv_deg[i] = 1.0f / (float)s;
  }
}

// ---------- per-node projections: A[b,i,c]=seq[b,i]@W[0:64]+b1, B[b,i,c]=seq[b,i]@W[64:128]
__global__ __launch_bounds__(256) void proj_kernel(const float* __restrict__ seq,
                                                   const float* __restrict__ W1,
                                                   const float* __restrict__ b1,
                                                   float* __restrict__ Ap,
                                                   float* __restrict__ Bp) {
  int bi = blockIdx.x;  // b*N + i
  __shared__ float sq[Uu];
  if (threadIdx.x < Uu) sq[threadIdx.x] = seq[bi * Uu + threadIdx.x];
  __syncthreads();
  for (int c = threadIdx.x; c < 2 * DIN; c += 256) {
    int isB = (c >= DIN) ? 1 : 0;
    int cc = c - isB * DIN;
    const float* Wb = W1 + (isB ? Uu * DIN : 0);
    float acc = isB ? 0.f : b1[cc];
#pragma unroll
    for (int u = 0; u < Uu; ++u) acc = fmaf(sq[u], Wb[u * DIN + cc], acc);
    if (isB) Bp[bi * DIN + cc] = acc;
    else     Ap[bi * DIN + cc] = acc;
  }
}

// ---------- edge MLP + column reduction ----------
// block: 256 threads = 16 groups (columns j) x 16 lanes (9 comps each, c = l + 16r)
__global__ __launch_bounds__(256, 2) void edge_kernel(
    const float* __restrict__ Ap, const float* __restrict__ Bp,
    const float* __restrict__ W1, const float* __restrict__ W2,
    const float* __restrict__ b2p, const float* __restrict__ enc,
    const int* __restrict__ mask, const float* __restrict__ inv_deg,
    float* __restrict__ s_out) {
  const int tid = threadIdx.x;
  const int l = tid & 15;
  const int g = tid >> 4;
  const int b = blockIdx.z;
  const int jt = blockIdx.x * TJ;
  const int i0 = blockIdx.y * ILEN;
  const int j = jt + g;

  // W1 enc rows (128..143) slice kept in registers: w1e[k][r] = W1[(128+k)*144 + l + 16r]
  float w1e[Kk][9];
#pragma unroll
  for (int k = 0; k < Kk; ++k)
#pragma unroll
    for (int r = 0; r < 9; ++r)
      w1e[k][r] = W1[(2 * Uu + k) * DIN + l + 16 * r];

  float breg[9], w2r[9];
#pragma unroll
  for (int r = 0; r < 9; ++r) {
    breg[r] = Bp[(b * Nn + j) * DIN + l + 16 * r];
    w2r[r]  = W2[l + 16 * r];
  }
  const float b2 = b2p[0];

  __shared__ float enc_s[2][TJ * Kk];
  __shared__ float A_s[2][DIN];
  __shared__ float mk_s[2][TJ];
  __shared__ float idg_s[2];

  auto stage = [&](int i, int buf) {
    enc_s[buf][tid] = enc[(i * Nn + jt) * Kk + tid];  // 256 contiguous floats
    if (tid < DIN) {
      A_s[buf][tid] = Ap[(b * Nn + i) * DIN + tid];
    } else if (tid < DIN + TJ) {
      mk_s[buf][tid - DIN] = (float)mask[i * Nn + jt + (tid - DIN)];
    } else if (tid == DIN + TJ) {
      idg_s[buf] = inv_deg[i];
    }
  };

  float sacc = 0.f;
  stage(i0, 0);
  __syncthreads();
  int buf = 0;
  for (int i = i0; i < i0 + ILEN; ++i, buf ^= 1) {
    if (i + 1 < i0 + ILEN) stage(i + 1, buf ^ 1);

    const float4* ep = reinterpret_cast<const float4*>(&enc_s[buf][g * Kk]);
    float4 e0 = ep[0], e1 = ep[1], e2 = ep[2], e3 = ep[3];
    float e[16] = {e0.x, e0.y, e0.z, e0.w, e1.x, e1.y, e1.z, e1.w,
                   e2.x, e2.y, e2.z, e2.w, e3.x, e3.y, e3.z, e3.w};

    float z[9];
#pragma unroll
    for (int r = 0; r < 9; ++r) z[r] = A_s[buf][l + 16 * r] + breg[r];
#pragma unroll
    for (int k = 0; k < Kk; ++k)
#pragma unroll
      for (int r = 0; r < 9; ++r)
        z[r] = fmaf(e[k], w1e[k][r], z[r]);

    float dot = 0.f;
#pragma unroll
    for (int r = 0; r < 9; ++r) {
      float h = fmaxf(z[r], 0.01f * z[r]);  // leaky_relu, slope in (0,1)
      dot = fmaf(h, w2r[r], dot);
    }
#pragma unroll
    for (int off = 1; off < 16; off <<= 1) dot += __shfl_xor(dot, off, 64);

    float w = dot + b2;
    w = fmaxf(w, 0.01f * w);
    sacc = fmaf(mk_s[buf][g] * idg_s[buf], w, sacc);
    __syncthreads();
  }
  if (l == 0) atomicAdd(&s_out[b * Nn + j], sacc);
}

// ---------- seq' = s * seq ----------
__global__ __launch_bounds__(256) void scale_kernel(const float* __restrict__ s,
                                                    const float* __restrict__ seq_in,
                                                    float* __restrict__ seq_out) {
  int idx = blockIdx.x * 256 + threadIdx.x;
  seq_out[idx] = s[idx >> 6] * seq_in[idx];
}

extern "C" void kernel_launch(void* const* d_in, const int* in_sizes, int n_in,
                              void* d_out, int out_size, void* d_ws, size_t ws_size,
                              hipStream_t stream) {
  const float* seq  = (const float*)d_in[0];
  const float* enc  = (const float*)d_in[1];
  const int*   mask = (const int*)d_in[2];
  const float* W11  = (const float*)d_in[3];
  const float* b11  = (const float*)d_in[4];
  const float* W12  = (const float*)d_in[5];
  const float* b12  = (const float*)d_in[6];
  const float* W21  = (const float*)d_in[7];
  const float* b21  = (const float*)d_in[8];
  const float* W22  = (const float*)d_in[9];
  const float* b22  = (const float*)d_in[10];
  float* out = (float*)d_out;

  float* ws      = (float*)d_ws;
  float* inv_deg = ws;                       // 768
  float* Ap      = ws + 1024;                // B*N*144
  float* Bp      = Ap + Bb * Nn * DIN;       // B*N*144
  float* sacc    = Bp + Bb * Nn * DIN;       // B*N
  float* seq_mid = sacc + 2048;              // B*N*U

  deg_kernel<<<Nn, 256, 0, stream>>>(mask, inv_deg);

  // hop 1
  proj_kernel<<<Bb * Nn, 256, 0, stream>>>(seq, W11, b11, Ap, Bp);
  hipMemsetAsync(sacc, 0, Bb * Nn * sizeof(float), stream);
  edge_kernel<<<dim3(Nn / TJ, ICH, Bb), 256, 0, stream>>>(Ap, Bp, W11, W12, b12,
                                                          enc, mask, inv_deg, sacc);
  scale_kernel<<<Bb * Nn * Uu / 256, 256, 0, stream>>>(sacc, seq, seq_mid);

  // hop 2
  proj_kernel<<<Bb * Nn, 256, 0, stream>>>(seq_mid, W21, b21, Ap, Bp);
  hipMemsetAsync(sacc, 0, Bb * Nn * sizeof(float), stream);
  edge_kernel<<<dim3(Nn / TJ, ICH, Bb), 256, 0, stream>>>(Ap, Bp, W21, W22, b22,
                                                          enc, mask, inv_deg, sacc);
  scale_kernel<<<Bb * Nn * Uu / 256, 256, 0, stream>>>(sacc, seq_mid, out);
}

// Round 2
// 247.586 us; speedup vs baseline: 2.1442x; 2.1442x over previous
//
#include <hip/hip_runtime.h>

#define Nn   768
#define Bb   2
#define Uu   64
#define Kk   16
#define DIN  144   // 2U+K
#define TJ   16    // columns per block
#define ICH  32    // i-chunks
#define ILEN (Nn / ICH)  // 24 rows per block
#define CH   8     // rows per staged chunk
#define NCH  (ILEN / CH) // 3

// ---------- degree ----------
__global__ __launch_bounds__(256) void deg_kernel(const int* __restrict__ mask,
                                                  float* __restrict__ inv_deg) {
  int i = blockIdx.x;
  int t = threadIdx.x;
  int sum = 0;
  for (int j = t; j < Nn; j += 256) sum += mask[i * Nn + j];
  for (int off = 32; off > 0; off >>= 1) sum += __shfl_down(sum, off, 64);
  __shared__ int partial[4];
  if ((t & 63) == 0) partial[t >> 6] = sum;
  __syncthreads();
  if (t == 0) {
    int s = partial[0] + partial[1] + partial[2] + partial[3];
    inv_deg[i] = 1.0f / (float)s;
  }
}

// ---------- per-node projections ----------
__global__ __launch_bounds__(256) void proj_kernel(const float* __restrict__ seq,
                                                   const float* __restrict__ W1,
                                                   const float* __restrict__ b1,
                                                   float* __restrict__ Ap,
                                                   float* __restrict__ Bp) {
  int bi = blockIdx.x;  // b*N + i
  __shared__ float sq[Uu];
  if (threadIdx.x < Uu) sq[threadIdx.x] = seq[bi * Uu + threadIdx.x];
  __syncthreads();
  for (int c = threadIdx.x; c < 2 * DIN; c += 256) {
    int isB = (c >= DIN) ? 1 : 0;
    int cc = c - isB * DIN;
    const float* Wb = W1 + (isB ? Uu * DIN : 0);
    float acc = isB ? 0.f : b1[cc];
#pragma unroll
    for (int u = 0; u < Uu; ++u) acc = fmaf(sq[u], Wb[u * DIN + cc], acc);
    if (isB) Bp[bi * DIN + cc] = acc;
    else     Ap[bi * DIN + cc] = acc;
  }
}

// ---------- edge MLP + column reduction, both batches fused ----------
// block: 256 threads = 16 groups (columns j) x 16 lanes (9 z-comps each, c = l + 16r)
__global__ __launch_bounds__(256, 2) void edge_kernel(
    const float* __restrict__ Ap, const float* __restrict__ Bp,
    const float* __restrict__ W1, const float* __restrict__ W2,
    const float* __restrict__ b2p, const float* __restrict__ enc,
    const int* __restrict__ mask, const float* __restrict__ inv_deg,
    float* __restrict__ s_out) {
  const int tid = threadIdx.x;
  const int l = tid & 15;
  const int g = tid >> 4;
  const int jt = blockIdx.x * TJ;
  const int i0 = blockIdx.y * ILEN;
  const int j = jt + g;

  // enc-rows slice of W1, pinned in registers (144 VGPRs)
  float w1e[Kk][9];
#pragma unroll
  for (int k = 0; k < Kk; ++k)
#pragma unroll
    for (int r = 0; r < 9; ++r)
      w1e[k][r] = W1[(2 * Uu + k) * DIN + l + 16 * r];
#pragma unroll
  for (int k = 0; k < Kk; ++k)
#pragma unroll
    for (int r = 0; r < 9; ++r)
      asm volatile("" : "+v"(w1e[k][r]));

  float breg0[9], breg1[9], w2r[9];
#pragma unroll
  for (int r = 0; r < 9; ++r) {
    breg0[r] = Bp[j * DIN + l + 16 * r];
    breg1[r] = Bp[(Nn + j) * DIN + l + 16 * r];
    w2r[r]   = W2[l + 16 * r];
  }
#pragma unroll
  for (int r = 0; r < 9; ++r) {
    asm volatile("" : "+v"(breg0[r]));
    asm volatile("" : "+v"(breg1[r]));
    asm volatile("" : "+v"(w2r[r]));
  }
  const float b2 = b2p[0];

  __shared__ float enc_s[2][CH][TJ * Kk];
  __shared__ float A_s[2][Bb][CH][DIN];
  __shared__ float mk_s[2][CH][TJ];
  __shared__ float idg_s[2][CH];

  auto stage = [&](int c0, int buf) {
#pragma unroll
    for (int rr = 0; rr < CH; ++rr)
      enc_s[buf][rr][tid] = enc[((c0 + rr) * Nn + jt) * Kk + tid];
#pragma unroll
    for (int q = 0; q < (Bb * CH * DIN) / 256; ++q) {
      int idx = tid + 256 * q;
      int c = idx % DIN;
      int rowb = idx / DIN;       // 0..15
      int rr = rowb & (CH - 1);
      int bb = rowb >> 3;
      A_s[buf][bb][rr][c] = Ap[(bb * Nn + c0 + rr) * DIN + c];
    }
    if (tid < CH * TJ) {
      mk_s[buf][tid >> 4][tid & 15] = (float)mask[(c0 + (tid >> 4)) * Nn + jt + (tid & 15)];
    } else if (tid < CH * TJ + CH) {
      idg_s[buf][tid - CH * TJ] = inv_deg[c0 + tid - CH * TJ];
    }
  };

  float sacc0 = 0.f, sacc1 = 0.f;
  stage(i0, 0);
  __syncthreads();
  int buf = 0;
  for (int ch = 0; ch < NCH; ++ch, buf ^= 1) {
    if (ch + 1 < NCH) stage(i0 + (ch + 1) * CH, buf ^ 1);
#pragma unroll
    for (int rr = 0; rr < CH; ++rr) {
      const float4* ep = reinterpret_cast<const float4*>(&enc_s[buf][rr][g * Kk]);
      float4 e0 = ep[0], e1 = ep[1], e2 = ep[2], e3 = ep[3];
      float e[16] = {e0.x, e0.y, e0.z, e0.w, e1.x, e1.y, e1.z, e1.w,
                     e2.x, e2.y, e2.z, e2.w, e3.x, e3.y, e3.z, e3.w};

      float zc[9];
#pragma unroll
      for (int r = 0; r < 9; ++r) zc[r] = e[0] * w1e[0][r];
#pragma unroll
      for (int k = 1; k < Kk; ++k)
#pragma unroll
        for (int r = 0; r < 9; ++r) zc[r] = fmaf(e[k], w1e[k][r], zc[r]);

      float dot0 = 0.f, dot1 = 0.f;
#pragma unroll
      for (int r = 0; r < 9; ++r) {
        float a0 = A_s[buf][0][rr][l + 16 * r];
        float a1 = A_s[buf][1][rr][l + 16 * r];
        float z0 = zc[r] + a0 + breg0[r];
        float z1 = zc[r] + a1 + breg1[r];
        z0 = fmaxf(z0, 0.01f * z0);
        z1 = fmaxf(z1, 0.01f * z1);
        dot0 = fmaf(z0, w2r[r], dot0);
        dot1 = fmaf(z1, w2r[r], dot1);
      }
#pragma unroll
      for (int off = 1; off < 16; off <<= 1) {
        dot0 += __shfl_xor(dot0, off, 64);
        dot1 += __shfl_xor(dot1, off, 64);
      }
      float w0 = dot0 + b2;
      float w1v = dot1 + b2;
      w0  = fmaxf(w0, 0.01f * w0);
      w1v = fmaxf(w1v, 0.01f * w1v);
      float mi = mk_s[buf][rr][g] * idg_s[buf][rr];
      sacc0 = fmaf(mi, w0, sacc0);
      sacc1 = fmaf(mi, w1v, sacc1);
    }
    __syncthreads();
  }
  if (l == 0) {
    atomicAdd(&s_out[j], sacc0);
    atomicAdd(&s_out[Nn + j], sacc1);
  }
}

// ---------- seq' = s * seq ----------
__global__ __launch_bounds__(256) void scale_kernel(const float* __restrict__ s,
                                                    const float* __restrict__ seq_in,
                                                    float* __restrict__ seq_out) {
  int idx = blockIdx.x * 256 + threadIdx.x;
  seq_out[idx] = s[idx >> 6] * seq_in[idx];
}

extern "C" void kernel_launch(void* const* d_in, const int* in_sizes, int n_in,
                              void* d_out, int out_size, void* d_ws, size_t ws_size,
                              hipStream_t stream) {
  const float* seq  = (const float*)d_in[0];
  const float* enc  = (const float*)d_in[1];
  const int*   mask = (const int*)d_in[2];
  const float* W11  = (const float*)d_in[3];
  const float* b11  = (const float*)d_in[4];
  const float* W12  = (const float*)d_in[5];
  const float* b12  = (const float*)d_in[6];
  const float* W21  = (const float*)d_in[7];
  const float* b21  = (const float*)d_in[8];
  const float* W22  = (const float*)d_in[9];
  const float* b22  = (const float*)d_in[10];
  float* out = (float*)d_out;

  float* ws      = (float*)d_ws;
  float* inv_deg = ws;                       // 768
  float* Ap      = ws + 1024;                // B*N*144
  float* Bp      = Ap + Bb * Nn * DIN;       // B*N*144
  float* sacc    = Bp + Bb * Nn * DIN;       // B*N
  float* seq_mid = sacc + 2048;              // B*N*U

  deg_kernel<<<Nn, 256, 0, stream>>>(mask, inv_deg);

  // hop 1
  proj_kernel<<<Bb * Nn, 256, 0, stream>>>(seq, W11, b11, Ap, Bp);
  hipMemsetAsync(sacc, 0, Bb * Nn * sizeof(float), stream);
  edge_kernel<<<dim3(Nn / TJ, ICH), 256, 0, stream>>>(Ap, Bp, W11, W12, b12,
                                                      enc, mask, inv_deg, sacc);
  scale_kernel<<<Bb * Nn * Uu / 256, 256, 0, stream>>>(sacc, seq, seq_mid);

  // hop 2
  proj_kernel<<<Bb * Nn, 256, 0, stream>>>(seq_mid, W21, b21, Ap, Bp);
  hipMemsetAsync(sacc, 0, Bb * Nn * sizeof(float), stream);
  edge_kernel<<<dim3(Nn / TJ, ICH), 256, 0, stream>>>(Ap, Bp, W21, W22, b22,
                                                      enc, mask, inv_deg, sacc);
  scale_kernel<<<Bb * Nn * Uu / 256, 256, 0, stream>>>(sacc, seq_mid, out);
}

// Round 4
// 136.492 us; speedup vs baseline: 3.8894x; 1.8139x over previous
//
#include <hip/hip_runtime.h>

typedef __attribute__((ext_vector_type(8))) short bf16x8;
typedef __attribute__((ext_vector_type(16))) float f32x16;
typedef __attribute__((ext_vector_type(4))) float f32x4;

__device__ inline unsigned short f2bf_rne(float x) {
  unsigned u = __float_as_uint(x);
  unsigned r = u + 0x7FFFu + ((u >> 16) & 1u);
  return (unsigned short)(r >> 16);
}
__device__ inline float bf2f(unsigned short h) {
  return __uint_as_float(((unsigned)h) << 16);
}

// ---------- P0: mprep[i,j] = mask[i,j] / deg[i] ----------
__global__ __launch_bounds__(256) void deg_mprep_kernel(const int* __restrict__ mask,
                                                        float* __restrict__ mprep) {
  int i = blockIdx.x, t = threadIdx.x;
  int sum = 0;
  for (int j = t; j < 768; j += 256) sum += mask[i*768 + j];
  for (int off = 32; off; off >>= 1) sum += __shfl_down(sum, off, 64);
  __shared__ int part[4];
  __shared__ float inv_s;
  if ((t & 63) == 0) part[t >> 6] = sum;
  __syncthreads();
  if (t == 0) inv_s = 1.0f / (float)(part[0] + part[1] + part[2] + part[3]);
  __syncthreads();
  float inv = inv_s;
  for (int j = t; j < 768; j += 256) mprep[i*768 + j] = (float)mask[i*768 + j] * inv;
}

// ---------- P1: per-node A (hi/lo bf16 packed) and Zej (fp32) ----------
// A[b,n,c]   = seq[b,n]@W1[0:64,c] + b1[c]      (e_i rows, consumed via MFMA af trick)
// Zej[b,n,c] = seq[b,n]@W1[64:128,c]            (e_j rows, consumed as fp32 C-init)
__global__ __launch_bounds__(256) void prep_kernel(const float* __restrict__ seq,
                                                   const float* __restrict__ W1,
                                                   const float* __restrict__ b1,
                                                   unsigned* __restrict__ apk,
                                                   float* __restrict__ zej) {
  int bi = blockIdx.x;  // b*768 + n
  __shared__ float sq[64];
  if (threadIdx.x < 64) sq[threadIdx.x] = seq[bi*64 + threadIdx.x];
  __syncthreads();
  int c = threadIdx.x;
  if (c < 160) {
    float accA = 0.f, accZ = 0.f;
    if (c < 144) {
      accA = b1[c];
#pragma unroll
      for (int u = 0; u < 64; ++u) accA = fmaf(sq[u], W1[u*144 + c], accA);
#pragma unroll
      for (int u = 0; u < 64; ++u) accZ = fmaf(sq[u], W1[(64 + u)*144 + c], accZ);
    }
    unsigned short hi = f2bf_rne(accA);
    unsigned short lo = f2bf_rne(accA - bf2f(hi));
    if (c >= 144) { hi = 0; lo = 0; }
    apk[bi*160 + c] = (unsigned)hi | ((unsigned)lo << 16);
    zej[bi*160 + c] = accZ;
  }
}

// ---------- P2: W1 enc-rows as A-operand fragments + padded w2 ----------
__global__ __launch_bounds__(256) void wpk_kernel(const float* __restrict__ W1,
                                                  const float* __restrict__ W2,
                                                  unsigned* __restrict__ wpk,
                                                  float* __restrict__ w2pad) {
  int g = blockIdx.x*256 + threadIdx.x;
  if (g < 1280) {
    int ew = g & 3;
    int l = (g >> 2) & 63;
    int t = g >> 8;                 // c-tile 0..4
    int c = t*32 + (l & 31);
    unsigned short h[2];
#pragma unroll
    for (int q = 0; q < 2; ++q) {
      int e = ew*2 + q;
      int koff = (l >> 5)*8 + e;    // k-channel 0..15
      float v = (c < 144) ? W1[(128 + koff)*144 + c] : 0.f;
      h[q] = f2bf_rne(v);
    }
    wpk[g] = (unsigned)h[0] | ((unsigned)h[1] << 16);
  } else if (g < 1440) {
    int c = g - 1280;
    w2pad[c] = (c < 144) ? W2[c] : 0.f;
  }
}

// ---------- edge kernel: 5 waves = 5 c-tiles of 32; 3 MFMA per (i) ----------
__global__ __launch_bounds__(320) void edge_kernel(
    const float* __restrict__ enc, const unsigned* __restrict__ apk,
    const float* __restrict__ zej, const unsigned* __restrict__ wpk,
    const float* __restrict__ w2pad, const float* __restrict__ b2p,
    const float* __restrict__ mprep, float* __restrict__ s_out) {
  const int tid = threadIdx.x;
  const int lane = tid & 63;
  const int w = tid >> 6;          // c-tile 0..4
  const int jb = blockIdx.x;       // 0..23
  const int i0 = blockIdx.y * 12;  // 64 i-blocks
  const int l31 = lane & 31, lh = lane >> 5;
  const int jglob = jb*32 + l31;

  bf16x8 wfrag = ((const bf16x8*)wpk)[w*64 + lane];

  float w2own[16];
#pragma unroll
  for (int r = 0; r < 16; ++r)
    w2own[r] = w2pad[w*32 + (r & 3) + 8*(r >> 2) + 4*lh];

  // Zej fragments (fp32, C/D layout): Cz0 = b=0 init, dz = b1 - b0
  f32x16 Cz0;
  float dz[16];
#pragma unroll
  for (int q = 0; q < 4; ++q) {
    f32x4 z0 = *(const f32x4*)&zej[(0*768 + jglob)*160 + w*32 + 4*lh + 8*q];
    f32x4 z1 = *(const f32x4*)&zej[(768   + jglob)*160 + w*32 + 4*lh + 8*q];
#pragma unroll
    for (int m = 0; m < 4; ++m) {
      Cz0[q*4 + m] = z0[m];
      dz[q*4 + m]  = z1[m] - z0[m];
    }
  }

  bf16x8 ones;
#pragma unroll
  for (int e = 0; e < 8; ++e) ones[e] = 0;
  if (lh == 0) { ones[0] = (short)0x3F80; ones[1] = (short)0x3F80; }

  __shared__ float pdot[5][2][24][32];
  __shared__ float scomb[256];
  const float b2 = *b2p;

#pragma unroll 2
  for (int il = 0; il < 12; ++il) {
    const int i = i0 + il;
    const float* ep = enc + ((size_t)(i*768 + jglob) << 4) + lh*8;
    f32x4 ea = *(const f32x4*)ep;
    f32x4 eb = *(const f32x4*)(ep + 4);
    bf16x8 encf;
    encf[0] = (short)f2bf_rne(ea[0]);
    encf[1] = (short)f2bf_rne(ea[1]);
    encf[2] = (short)f2bf_rne(ea[2]);
    encf[3] = (short)f2bf_rne(ea[3]);
    encf[4] = (short)f2bf_rne(eb[0]);
    encf[5] = (short)f2bf_rne(eb[1]);
    encf[6] = (short)f2bf_rne(eb[2]);
    encf[7] = (short)f2bf_rne(eb[3]);

    // Ce = Zej0 + W1enc^T · enc
    f32x16 Ce = __builtin_amdgcn_mfma_f32_32x32x16_bf16(wfrag, encf, Cz0, 0, 0, 0);
    f32x16 C1;
#pragma unroll
    for (int r = 0; r < 16; ++r) C1[r] = Ce[r] + dz[r];

    unsigned av0 = 0, av1 = 0;
    if (lh == 0) {
      av0 = apk[(0*768 + i)*160 + w*32 + l31];
      av1 = apk[(768   + i)*160 + w*32 + l31];
    }
    bf16x8 af0, af1;
#pragma unroll
    for (int e = 0; e < 8; ++e) { af0[e] = 0; af1[e] = 0; }
    af0[0] = (short)(av0 & 0xFFFFu); af0[1] = (short)(av0 >> 16);
    af1[0] = (short)(av1 & 0xFFFFu); af1[1] = (short)(av1 >> 16);

    f32x16 Cb0 = __builtin_amdgcn_mfma_f32_32x32x16_bf16(af0, ones, Ce, 0, 0, 0);
    f32x16 Cb1 = __builtin_amdgcn_mfma_f32_32x32x16_bf16(af1, ones, C1, 0, 0, 0);

    float dp0 = 0.f, dp1 = 0.f;
#pragma unroll
    for (int r = 0; r < 16; ++r) {
      float z0 = Cb0[r], z1 = Cb1[r];
      float h0 = fmaxf(z0, 0.01f*z0);
      float h1 = fmaxf(z1, 0.01f*z1);
      dp0 = fmaf(h0, w2own[r], dp0);
      dp1 = fmaf(h1, w2own[r], dp1);
    }
    pdot[w][lh][il*2 + 0][l31] = dp0;
    pdot[w][lh][il*2 + 1][l31] = dp1;
  }
  __syncthreads();

  if (tid < 256) {
    const int j = tid & 31, isub = (tid >> 5) & 3, b = tid >> 7;
    float sacc_t = 0.f;
#pragma unroll
    for (int k3 = 0; k3 < 3; ++k3) {
      const int il = isub + k3*4;
      const int unit = il*2 + b;
      float sum = 0.f;
#pragma unroll
      for (int w5 = 0; w5 < 5; ++w5)
        sum += pdot[w5][0][unit][j] + pdot[w5][1][unit][j];
      float wv = sum + b2;
      wv = fmaxf(wv, 0.01f*wv);
      sacc_t = fmaf(mprep[(i0 + il)*768 + jb*32 + j], wv, sacc_t);
    }
    scomb[tid] = sacc_t;   // scomb[b*128 + isub*32 + j]
  }
  __syncthreads();
  if (tid < 64) {
    const int b = tid >> 5, j = tid & 31;
    float tot = 0.f;
#pragma unroll
    for (int isub = 0; isub < 4; ++isub)
      tot += scomb[b*128 + isub*32 + j];   // FIXED combine indexing
    atomicAdd(&s_out[b*768 + jb*32 + j], tot);
  }
}

// ---------- seq' = s * seq ----------
__global__ __launch_bounds__(256) void scale_kernel(const float* __restrict__ s,
                                                    const float* __restrict__ seq_in,
                                                    float* __restrict__ seq_out) {
  int idx = blockIdx.x * 256 + threadIdx.x;
  seq_out[idx] = s[idx >> 6] * seq_in[idx];
}

extern "C" void kernel_launch(void* const* d_in, const int* in_sizes, int n_in,
                              void* d_out, int out_size, void* d_ws, size_t ws_size,
                              hipStream_t stream) {
  const float* seq  = (const float*)d_in[0];
  const float* enc  = (const float*)d_in[1];
  const int*   mask = (const int*)d_in[2];
  const float* W11  = (const float*)d_in[3];
  const float* b11  = (const float*)d_in[4];
  const float* W12  = (const float*)d_in[5];
  const float* b12  = (const float*)d_in[6];
  const float* W21  = (const float*)d_in[7];
  const float* b21  = (const float*)d_in[8];
  const float* W22  = (const float*)d_in[9];
  const float* b22  = (const float*)d_in[10];
  float* out = (float*)d_out;

  float* ws = (float*)d_ws;
  size_t off = 0;
  float* mprep = ws + off;                 off += 768*768;
  unsigned* apk = (unsigned*)(ws + off);   off += 2*768*160;
  float* zej = ws + off;                   off += 2*768*160;
  unsigned* wpk = (unsigned*)(ws + off);   off += 1280;
  float* w2pad = ws + off;                 off += 160;
  float* sacc  = ws + off;                 off += 2*768;
  float* seq_mid = ws + off;               off += 2*768*64;

  deg_mprep_kernel<<<768, 256, 0, stream>>>(mask, mprep);

  // hop 1
  prep_kernel<<<1536, 256, 0, stream>>>(seq, W11, b11, apk, zej);
  wpk_kernel<<<6, 256, 0, stream>>>(W11, W12, wpk, w2pad);
  hipMemsetAsync(sacc, 0, 1536*sizeof(float), stream);
  edge_kernel<<<dim3(24, 64), 320, 0, stream>>>(enc, apk, zej, wpk, w2pad, b12, mprep, sacc);
  scale_kernel<<<384, 256, 0, stream>>>(sacc, seq, seq_mid);

  // hop 2
  prep_kernel<<<1536, 256, 0, stream>>>(seq_mid, W21, b21, apk, zej);
  wpk_kernel<<<6, 256, 0, stream>>>(W21, W22, wpk, w2pad);
  hipMemsetAsync(sacc, 0, 1536*sizeof(float), stream);
  edge_kernel<<<dim3(24, 64), 320, 0, stream>>>(enc, apk, zej, wpk, w2pad, b22, mprep, sacc);
  scale_kernel<<<384, 256, 0, stream>>>(sacc, seq_mid, out);
}